// Round 2
// baseline (200.458 us; speedup 1.0000x reference)
//
#include <hip/hip_runtime.h>
#include <stdint.h>

#define U 128
#define V 128
#define IN_STRIDE 512
#define OUT_STRIDE 512
#define W_STRIDE (8 * U * V) /* 131072 floats per expert */
#define NB 32768
#define NE 4

// Workspace layout (bytes)
#define WS_WSHUF 0           // 524288 ushorts (1 MB) shuffled bf16 weights
#define WS_CNT   1048576     // 4 uint per-expert cursors/counts (16 B)
#define WS_SORT  1048640     // 4 * 32768 ints (512 KB): region e at e*NB

typedef __bf16 bf16x8 __attribute__((ext_vector_type(8)));
typedef float f32x16 __attribute__((ext_vector_type(16)));
typedef unsigned int u32x4 __attribute__((ext_vector_type(4)));

static __device__ __forceinline__ unsigned short f2bf(float f) {
    unsigned int u = __builtin_bit_cast(unsigned int, f);
    u += 0x7FFFu + ((u >> 16) & 1u);   // round-to-nearest-even
    return (unsigned short)(u >> 16);
}

// ---------------------------------------------------------------------------
// prep: weights fp32 -> bf16 in MFMA B-fragment layout (unchanged layout).
//   flat short index = ((((e*8+s)*4+nt)*8+kt)*64+lane)*8 + j
//   element = W[e][s][k = kt*16+(lane>>5)*8+j][n = nt*32+(lane&31)], segs 4..7 x0.5
// Also zeroes the 4 expert cursors (stream order guarantees visibility).
// ---------------------------------------------------------------------------
__global__ void prep_kernel(const float* __restrict__ w, unsigned short* __restrict__ wshuf,
                            unsigned int* __restrict__ cnt) {
    if (blockIdx.x == 0 && threadIdx.x < NE) cnt[threadIdx.x] = 0u;
    int t = blockIdx.x * 256 + threadIdx.x;   // 0..65535
    int lane = t & 63;
    int kt = (t >> 6) & 7;
    int nt = (t >> 9) & 3;
    int s  = (t >> 11) & 7;
    int e  = (t >> 14) & 3;
    int kbase = kt * 16 + ((lane >> 5) << 3);
    int n = nt * 32 + (lane & 31);
    const float* src = w + (size_t)e * W_STRIDE + (size_t)s * (U * V) + n;
    float sc = (s >= 4) ? 0.5f : 1.0f;
    __attribute__((aligned(16))) unsigned short o[8];
#pragma unroll
    for (int j = 0; j < 8; j++) o[j] = f2bf(src[(size_t)(kbase + j) * V] * sc);
    *(u32x4*)(wshuf + (size_t)t * 8) = *(const u32x4*)o;
}

// ---------------------------------------------------------------------------
// scatter: bucket rows by expert (order within expert irrelevant).
// ---------------------------------------------------------------------------
__global__ void scatter_kernel(const int* __restrict__ wid, unsigned int* __restrict__ cnt,
                               int* __restrict__ sorted) {
    __shared__ unsigned int lcnt[NE];
    __shared__ unsigned int lbase[NE];
    int t = threadIdx.x;
    if (t < NE) lcnt[t] = 0u;
    __syncthreads();
    int i = blockIdx.x * 256 + t;
    int e = wid[i];
    unsigned int lpos = atomicAdd(&lcnt[e], 1u);
    __syncthreads();
    if (t < NE) lbase[t] = atomicAdd(&cnt[t], lcnt[t]);
    __syncthreads();
    sorted[e * NB + (int)(lbase[e] + lpos)] = i;
}

// ---------------------------------------------------------------------------
// gemm R6: NO LDS, NO barriers. 1024 blocks x 256 threads; block = 32 sorted
// rows, wave w = kout (output col block). A fragments are gathered DIRECTLY
// from global: lane l needs 8 consecutive floats of row (l&31) at k-chunk
// (l>>5)*8 -> two dwordx4 off one per-lane row pointer (immediate offsets),
// converted to bf16 in flight. Each x col-block is read by 2 waves of the
// same block (2nd hits L2). Pure streaming: waves independently pipeline
// loads+MFMA, no phase sync -> memory latency hidden by 16 waves/CU at
// different phases instead of a barrier-serialized stage.
// K=256 per kout: x-block kout (seg kout) ++ x-block (kout+3)&3 (seg +4,
// x0.5 pre-folded in prep). Fast path when the 32-row group is single-expert
// (>=1021 of 1024 blocks); masked 4-expert path otherwise.
// ---------------------------------------------------------------------------
__global__ __launch_bounds__(256, 4) void gemm_kernel(
        const float* __restrict__ x, const unsigned short* __restrict__ wshuf,
        const unsigned int* __restrict__ cnt, const int* __restrict__ sorted,
        float* __restrict__ out) {
    const int rowbase = blockIdx.x * 32;
    const unsigned int p1 = cnt[0];
    const unsigned int p2 = p1 + cnt[1];
    const unsigned int p3 = p2 + cnt[2];

    const int t = threadIdx.x;
    const int kout = t >> 6;           // wave id = output col block
    const int lane = t & 63;
    const int m0 = lane & 31;
    const int khalf = lane >> 5;       // 0/1: k-offset/8 within k-tile

    // A-row for this lane (sorted-order position -> actual row)
    const unsigned int l0 = (unsigned int)(rowbase + m0);
    const int e0 = (l0 >= p1) + (l0 >= p2) + (l0 >= p3);
    const unsigned int pe0 = (e0 == 0) ? 0u : (e0 == 1) ? p1 : (e0 == 2) ? p2 : p3;
    const int arow = sorted[e0 * NB + (int)(l0 - pe0)];
    const float* xr = x + (size_t)arow * IN_STRIDE + khalf * 8;

    // expert span of the whole 32-row group
    const unsigned int lh = (unsigned int)rowbase, lt = (unsigned int)(rowbase + 31);
    const int ehead = (lh >= p1) + (lh >= p2) + (lh >= p3);
    const int etail = (lt >= p1) + (lt >= p2) + (lt >= p3);

    const int xbs1 = (kout + 3) & 3;
    int xbs[2] = {kout, xbs1};
    int sgs[2] = {kout, xbs1 + 4};

    f32x16 acc[4] = {};   // acc[nt]: cols kout*128 + nt*32 + (lane&31)

    if (ehead == etail) {
        // ---- fast path: whole 32-row group is one expert ----
        const int eu = ehead;
#pragma unroll
        for (int c = 0; c < 2; c++) {
            // nt-dim stride is 8*512 = 4096 shorts
            const unsigned short* wb =
                wshuf + (size_t)((eu * 8 + sgs[c]) * 4) * 4096 + (size_t)lane * 8;
            const float* xc = xr + xbs[c] * 128;
#pragma unroll
            for (int kt = 0; kt < 8; kt++) {
                float4 va = *(const float4*)(xc + kt * 16);
                float4 vb = *(const float4*)(xc + kt * 16 + 4);
                bf16x8 a;
                a[0] = (__bf16)va.x; a[1] = (__bf16)va.y;
                a[2] = (__bf16)va.z; a[3] = (__bf16)va.w;
                a[4] = (__bf16)vb.x; a[5] = (__bf16)vb.y;
                a[6] = (__bf16)vb.z; a[7] = (__bf16)vb.w;
#pragma unroll
                for (int nt = 0; nt < 4; nt++) {
                    bf16x8 b = __builtin_bit_cast(bf16x8,
                        *(const u32x4*)(wb + (size_t)(nt * 8 + kt) * 512));
                    acc[nt] = __builtin_amdgcn_mfma_f32_32x32x16_bf16(a, b, acc[nt], 0, 0, 0);
                }
            }
        }
    } else {
        // ---- boundary group (<=3 of 1024): masked 4-expert path ----
        unsigned int msk[4];
#pragma unroll
        for (int e = 0; e < 4; e++) msk[e] = (e0 == e) ? 0xFFFFFFFFu : 0u;
#pragma unroll
        for (int c = 0; c < 2; c++) {
            const float* xc = xr + xbs[c] * 128;
#pragma unroll
            for (int kt = 0; kt < 8; kt++) {
                float4 va = *(const float4*)(xc + kt * 16);
                float4 vb = *(const float4*)(xc + kt * 16 + 4);
                __attribute__((aligned(16))) unsigned short au[8];
                au[0] = f2bf(va.x); au[1] = f2bf(va.y);
                au[2] = f2bf(va.z); au[3] = f2bf(va.w);
                au[4] = f2bf(vb.x); au[5] = f2bf(vb.y);
                au[6] = f2bf(vb.z); au[7] = f2bf(vb.w);
                u32x4 araw = *(const u32x4*)au;
#pragma unroll
                for (int e = 0; e < 4; e++) {
                    u32x4 mm = {msk[e], msk[e], msk[e], msk[e]};
                    bf16x8 am = __builtin_bit_cast(bf16x8, araw & mm);
                    const unsigned short* wb =
                        wshuf + (size_t)((e * 8 + sgs[c]) * 4) * 4096 + (size_t)lane * 8;
#pragma unroll
                    for (int nt = 0; nt < 4; nt++) {
                        bf16x8 b = __builtin_bit_cast(bf16x8,
                            *(const u32x4*)(wb + (size_t)(nt * 8 + kt) * 512));
                        acc[nt] = __builtin_amdgcn_mfma_f32_32x32x16_bf16(am, b, acc[nt], 0, 0, 0);
                    }
                }
            }
        }
    }

    // ---- epilogue: C/D layout col=lane&31, row=(reg&3)+8*(reg>>2)+4*(lane>>5)
    // per store instr: half-wave writes 128B contiguous (rows scattered via sorted).
    const int colb = kout * 128 + m0;
    const int rh = khalf << 2;
#pragma unroll
    for (int q = 0; q < 4; q++) {
#pragma unroll
        for (int d = 0; d < 4; d++) {
            int reg = q * 4 + d;
            unsigned int ls = (unsigned int)(rowbase + d + 8 * q + rh);
            int es = (ls >= p1) + (ls >= p2) + (ls >= p3);
            unsigned int pes = (es == 0) ? 0u : (es == 1) ? p1 : (es == 2) ? p2 : p3;
            int orow = sorted[es * NB + (int)(ls - pes)];
            float* o = out + (size_t)orow * OUT_STRIDE + colb;
            o[0]  = acc[0][reg];
            o[32] = acc[1][reg];
            o[64] = acc[2][reg];
            o[96] = acc[3][reg];
        }
    }
}

extern "C" void kernel_launch(void* const* d_in, const int* in_sizes, int n_in,
                              void* d_out, int out_size, void* d_ws, size_t ws_size,
                              hipStream_t stream) {
    const float* x = (const float*)d_in[0];
    const float* w = (const float*)d_in[1];
    const int* wid = (const int*)d_in[2];
    float* out = (float*)d_out;

    unsigned short* wshuf = (unsigned short*)((char*)d_ws + WS_WSHUF);
    unsigned int* cnt = (unsigned int*)((char*)d_ws + WS_CNT);
    int* sorted = (int*)((char*)d_ws + WS_SORT);

    prep_kernel<<<256, 256, 0, stream>>>(w, wshuf, cnt);
    scatter_kernel<<<128, 256, 0, stream>>>(wid, cnt, sorted);
    gemm_kernel<<<1024, 256, 0, stream>>>(x, wshuf, cnt, sorted, out);
}

// Round 3
// 168.195 us; speedup vs baseline: 1.1918x; 1.1918x over previous
//
#include <hip/hip_runtime.h>
#include <stdint.h>

#define U 128
#define V 128
#define IN_STRIDE 512
#define OUT_STRIDE 512
#define W_STRIDE (8 * U * V) /* 131072 floats per expert */
#define NB 32768
#define NE 4

// Workspace layout (bytes)
#define WS_WSHUF 0           // 524288 ushorts (1 MB) shuffled bf16 weights
#define WS_CNT   1048576     // 4 uint per-expert cursors/counts (16 B)
#define WS_SORT  1048640     // 4 * 32768 ints (512 KB): region e at e*NB

typedef __bf16 bf16x8 __attribute__((ext_vector_type(8)));
typedef float f32x16 __attribute__((ext_vector_type(16)));
typedef unsigned int u32x4 __attribute__((ext_vector_type(4)));

static __device__ __forceinline__ unsigned short f2bf(float f) {
    unsigned int u = __builtin_bit_cast(unsigned int, f);
    u += 0x7FFFu + ((u >> 16) & 1u);   // round-to-nearest-even
    return (unsigned short)(u >> 16);
}

// ---------------------------------------------------------------------------
// prep: weights fp32 -> bf16 in MFMA B-fragment layout (unchanged).
//   shorts offset = (((e*8+s)*4+nt)*8+kt)*512 + lane*8 + j
//   element = W[e][s][k = kt*16+(lane>>5)*8+j][n = nt*32+(lane&31)], segs 4..7 x0.5
// ---------------------------------------------------------------------------
__global__ void prep_kernel(const float* __restrict__ w, unsigned short* __restrict__ wshuf,
                            unsigned int* __restrict__ cnt) {
    if (blockIdx.x == 0 && threadIdx.x < NE) cnt[threadIdx.x] = 0u;
    int t = blockIdx.x * 256 + threadIdx.x;   // 0..65535
    int lane = t & 63;
    int kt = (t >> 6) & 7;
    int nt = (t >> 9) & 3;
    int s  = (t >> 11) & 7;
    int e  = (t >> 14) & 3;
    int kbase = kt * 16 + ((lane >> 5) << 3);
    int n = nt * 32 + (lane & 31);
    const float* src = w + (size_t)e * W_STRIDE + (size_t)s * (U * V) + n;
    float sc = (s >= 4) ? 0.5f : 1.0f;
    __attribute__((aligned(16))) unsigned short o[8];
#pragma unroll
    for (int j = 0; j < 8; j++) o[j] = f2bf(src[(size_t)(kbase + j) * V] * sc);
    *(u32x4*)(wshuf + (size_t)t * 8) = *(const u32x4*)o;
}

// ---------------------------------------------------------------------------
// scatter: bucket rows by expert (order within expert irrelevant).
// ---------------------------------------------------------------------------
__global__ void scatter_kernel(const int* __restrict__ wid, unsigned int* __restrict__ cnt,
                               int* __restrict__ sorted) {
    __shared__ unsigned int lcnt[NE];
    __shared__ unsigned int lbase[NE];
    int t = threadIdx.x;
    if (t < NE) lcnt[t] = 0u;
    __syncthreads();
    int i = blockIdx.x * 256 + t;
    int e = wid[i];
    unsigned int lpos = atomicAdd(&lcnt[e], 1u);
    __syncthreads();
    if (t < NE) lbase[t] = atomicAdd(&cnt[t], lcnt[t]);
    __syncthreads();
    sorted[e * NB + (int)(lbase[e] + lpos)] = i;
}

// ---------------------------------------------------------------------------
// gemm R7: counted-vmcnt 4-phase pipeline (T3+T4), fp32-in-LDS via
// global_load_lds. 1024 blocks x 256 thr (4 waves), tile = 32 sorted rows.
// LDS ldsf[4][32][128] fp32 (64 KB): phase p = x col-block p.
// Staging: wave w stages rows 8w..8w+7; per (p,i) one global_load_lds of 1 KB
// (lane<32 -> row 8w+2i, lane>=32 -> row 8w+2i+1; 512B contiguous per row).
// ALL 16 instrs issued at t=0; phase gates s_waitcnt vmcnt(12/8/4/0) +
// raw s_barrier keep later phases' loads in flight across barriers (never
// drain mid-kernel). Each wave's gate covers its own loads; barrier makes it
// collective (m201 pattern).
// Swizzle (rule #21, both-sides): global source chunk = (lane&31) ^ (r&7);
// fragment ds_read at chunk (gj ^ (m&7)) -> b128 reads at the structural
// 8-cycle floor (no bank conflicts). cvt fp32->bf16 at fragment-read time.
// Wave w owns out col-block w: computes at phases {w (c0, seg w),
// (w+3)&3 (c1, seg p+4)}. Fast single-expert path; masked path for the
// <=3 boundary blocks. Stores at end (overlap next block's loads).
// ---------------------------------------------------------------------------
__global__ __launch_bounds__(256, 2) void gemm_kernel(
        const float* __restrict__ x, const unsigned short* __restrict__ wshuf,
        const unsigned int* __restrict__ cnt, const int* __restrict__ sorted,
        float* __restrict__ out) {
    const int rowbase = blockIdx.x * 32;
    __shared__ float ldsf[4][32][128];   // 64 KB
    __shared__ int rowid[32];

    const unsigned int p1 = cnt[0];
    const unsigned int p2 = p1 + cnt[1];
    const unsigned int p3 = p2 + cnt[2];

    const int t = threadIdx.x;
    const int w = t >> 6, lane = t & 63;
    const int l5 = lane >> 5, m0 = lane & 31;

    // ---- prologue: row ids for this wave's 8 staged rows ----
    int rid[4];
    int sw[4];
#pragma unroll
    for (int i = 0; i < 4; i++) {
        unsigned int ls = (unsigned int)(rowbase + 8 * w + 2 * i + l5);
        int e = (ls >= p1) + (ls >= p2) + (ls >= p3);
        unsigned int pe = (e == 0) ? 0u : (e == 1) ? p1 : (e == 2) ? p2 : p3;
        rid[i] = sorted[e * NB + (int)(ls - pe)];
        sw[i] = (2 * i + l5) & 7;          // (tile-row & 7) of this lane's row
    }
    if (t < 32) {
        unsigned int ls = (unsigned int)(rowbase + t);
        int e = (ls >= p1) + (ls >= p2) + (ls >= p3);
        unsigned int pe = (e == 0) ? 0u : (e == 1) ? p1 : (e == 2) ? p2 : p3;
        rowid[t] = sorted[e * NB + (int)(ls - pe)];
    }
    asm volatile("" ::: "memory");   // pin rowid write before the barriers

    // ---- issue ALL 16 stage loads (4 phases x 4 rowpairs), phase-major ----
#pragma unroll
    for (int p = 0; p < 4; p++) {
#pragma unroll
        for (int i = 0; i < 4; i++) {
            const float* src = x + (size_t)rid[i] * IN_STRIDE + p * 128 + ((m0 ^ sw[i]) << 2);
            __builtin_amdgcn_global_load_lds(
                (const __attribute__((address_space(1))) unsigned int*)src,
                (__attribute__((address_space(3))) unsigned int*)&ldsf[p][8 * w + 2 * i][0],
                16, 0, 0);
        }
    }

    // expert span / per-lane expert for masked path
    const unsigned int lh = (unsigned int)rowbase, lt = (unsigned int)(rowbase + 31);
    const int ehead = (lh >= p1) + (lh >= p2) + (lh >= p3);
    const int etail = (lt >= p1) + (lt >= p2) + (lt >= p3);
    const int fast = (ehead == etail);
    const unsigned int l0 = (unsigned int)(rowbase + m0);
    const int e0 = (l0 >= p1) + (l0 >= p2) + (l0 >= p3);
    unsigned int msk[4];
#pragma unroll
    for (int e = 0; e < 4; e++) msk[e] = (e0 == e) ? 0xFFFFFFFFu : 0u;

    const int xbc0 = w, xbc1 = (w + 3) & 3;
    const int rsw = m0 & 7;
    f32x16 acc[4] = {};

#define GATE(N) do { \
        asm volatile("s_waitcnt vmcnt(" #N ")" ::: "memory"); \
        __builtin_amdgcn_sched_barrier(0); \
        __builtin_amdgcn_s_barrier(); \
        __builtin_amdgcn_sched_barrier(0); \
    } while (0)

#define COMPUTE(p) do { \
        int act = (p == xbc0) ? 1 : ((p == xbc1) ? 2 : 0); \
        if (act) { \
            int sg = (act == 1) ? w : (p + 4); \
            const float* ar = &ldsf[p][m0][0]; \
            if (fast) { \
                const unsigned short* wb = \
                    wshuf + (size_t)((ehead * 8 + sg) * 4) * 4096 + (size_t)lane * 8; \
                _Pragma("unroll") \
                for (int kt = 0; kt < 8; kt++) { \
                    int gj0 = kt * 4 + l5 * 2; \
                    float4 va = *(const float4*)(ar + ((gj0 ^ rsw) << 2)); \
                    float4 vb = *(const float4*)(ar + (((gj0 + 1) ^ rsw) << 2)); \
                    bf16x8 a; \
                    a[0] = (__bf16)va.x; a[1] = (__bf16)va.y; \
                    a[2] = (__bf16)va.z; a[3] = (__bf16)va.w; \
                    a[4] = (__bf16)vb.x; a[5] = (__bf16)vb.y; \
                    a[6] = (__bf16)vb.z; a[7] = (__bf16)vb.w; \
                    _Pragma("unroll") \
                    for (int nt = 0; nt < 4; nt++) { \
                        bf16x8 b = __builtin_bit_cast(bf16x8, \
                            *(const u32x4*)(wb + (size_t)(nt * 8 + kt) * 512)); \
                        acc[nt] = __builtin_amdgcn_mfma_f32_32x32x16_bf16(a, b, acc[nt], 0, 0, 0); \
                    } \
                } \
            } else { \
                _Pragma("unroll") \
                for (int kt = 0; kt < 8; kt++) { \
                    int gj0 = kt * 4 + l5 * 2; \
                    float4 va = *(const float4*)(ar + ((gj0 ^ rsw) << 2)); \
                    float4 vb = *(const float4*)(ar + (((gj0 + 1) ^ rsw) << 2)); \
                    __attribute__((aligned(16))) unsigned short au[8]; \
                    au[0] = f2bf(va.x); au[1] = f2bf(va.y); \
                    au[2] = f2bf(va.z); au[3] = f2bf(va.w); \
                    au[4] = f2bf(vb.x); au[5] = f2bf(vb.y); \
                    au[6] = f2bf(vb.z); au[7] = f2bf(vb.w); \
                    u32x4 araw = *(const u32x4*)au; \
                    _Pragma("unroll") \
                    for (int e = 0; e < 4; e++) { \
                        u32x4 mm = {msk[e], msk[e], msk[e], msk[e]}; \
                        bf16x8 am = __builtin_bit_cast(bf16x8, araw & mm); \
                        const unsigned short* wb = \
                            wshuf + (size_t)((e * 8 + sg) * 4) * 4096 + (size_t)lane * 8; \
                        _Pragma("unroll") \
                        for (int nt = 0; nt < 4; nt++) { \
                            bf16x8 b = __builtin_bit_cast(bf16x8, \
                                *(const u32x4*)(wb + (size_t)(nt * 8 + kt) * 512)); \
                            acc[nt] = __builtin_amdgcn_mfma_f32_32x32x16_bf16(am, b, acc[nt], 0, 0, 0); \
                        } \
                    } \
                } \
            } \
        } \
    } while (0)

    GATE(12); COMPUTE(0);
    GATE(8);  COMPUTE(1);
    GATE(4);  COMPUTE(2);
    GATE(0);  COMPUTE(3);

#undef GATE
#undef COMPUTE

    // ---- epilogue: C/D layout col=lane&31, row=(reg&3)+8*(reg>>2)+4*(lane>>5)
    // per store instr: 32 lanes write 128B contiguous; rows scattered via rowid.
    const int colb = w * 128 + m0;
    const int rh = l5 << 2;
#pragma unroll
    for (int q = 0; q < 4; q++) {
#pragma unroll
        for (int d = 0; d < 4; d++) {
            int reg = q * 4 + d;
            int rl = d + 8 * q + rh;
            float* o = out + (size_t)rowid[rl] * OUT_STRIDE + colb;
            o[0]  = acc[0][reg];
            o[32] = acc[1][reg];
            o[64] = acc[2][reg];
            o[96] = acc[3][reg];
        }
    }
}

extern "C" void kernel_launch(void* const* d_in, const int* in_sizes, int n_in,
                              void* d_out, int out_size, void* d_ws, size_t ws_size,
                              hipStream_t stream) {
    const float* x = (const float*)d_in[0];
    const float* w = (const float*)d_in[1];
    const int* wid = (const int*)d_in[2];
    float* out = (float*)d_out;

    unsigned short* wshuf = (unsigned short*)((char*)d_ws + WS_WSHUF);
    unsigned int* cnt = (unsigned int*)((char*)d_ws + WS_CNT);
    int* sorted = (int*)((char*)d_ws + WS_SORT);

    prep_kernel<<<256, 256, 0, stream>>>(w, wshuf, cnt);
    scatter_kernel<<<128, 256, 0, stream>>>(wid, cnt, sorted);
    gemm_kernel<<<1024, 256, 0, stream>>>(x, wshuf, cnt, sorted, out);
}

// Round 4
// 136.686 us; speedup vs baseline: 1.4666x; 1.2305x over previous
//
#include <hip/hip_runtime.h>
#include <stdint.h>

#define U 128
#define V 128
#define IN_STRIDE 512
#define OUT_STRIDE 512
#define W_STRIDE (8 * U * V) /* 131072 floats per expert */
#define NB 32768
#define NE 4

// Workspace layout (bytes)
#define WS_WSHUF 0           // 524288 ushorts (1 MB) shuffled bf16 weights
#define WS_CNT   1048576     // 4 uint per-expert cursors/counts (16 B)
#define WS_SORT  1048640     // 4 * 32768 ints (512 KB): region e at e*NB

typedef __bf16 bf16x8 __attribute__((ext_vector_type(8)));
typedef float f32x16 __attribute__((ext_vector_type(16)));
typedef unsigned int u32x4 __attribute__((ext_vector_type(4)));

static __device__ __forceinline__ unsigned short f2bf(float f) {
    unsigned int u = __builtin_bit_cast(unsigned int, f);
    u += 0x7FFFu + ((u >> 16) & 1u);   // round-to-nearest-even
    return (unsigned short)(u >> 16);
}

// ---------------------------------------------------------------------------
// prep: weights fp32 -> bf16 in MFMA B-fragment layout (unchanged).
//   shorts offset = (((e*8+s)*4+nt)*8+kt)*512 + lane*8 + j
//   element = W[e][s][k = kt*16+(lane>>5)*8+j][n = nt*32+(lane&31)], segs 4..7 x0.5
// ---------------------------------------------------------------------------
__global__ void prep_kernel(const float* __restrict__ w, unsigned short* __restrict__ wshuf,
                            unsigned int* __restrict__ cnt) {
    if (blockIdx.x == 0 && threadIdx.x < NE) cnt[threadIdx.x] = 0u;
    int t = blockIdx.x * 256 + threadIdx.x;   // 0..65535
    int lane = t & 63;
    int kt = (t >> 6) & 7;
    int nt = (t >> 9) & 3;
    int s  = (t >> 11) & 7;
    int e  = (t >> 14) & 3;
    int kbase = kt * 16 + ((lane >> 5) << 3);
    int n = nt * 32 + (lane & 31);
    const float* src = w + (size_t)e * W_STRIDE + (size_t)s * (U * V) + n;
    float sc = (s >= 4) ? 0.5f : 1.0f;
    __attribute__((aligned(16))) unsigned short o[8];
#pragma unroll
    for (int j = 0; j < 8; j++) o[j] = f2bf(src[(size_t)(kbase + j) * V] * sc);
    *(u32x4*)(wshuf + (size_t)t * 8) = *(const u32x4*)o;
}

// ---------------------------------------------------------------------------
// scatter: bucket rows by expert (order within expert irrelevant).
// ---------------------------------------------------------------------------
__global__ void scatter_kernel(const int* __restrict__ wid, unsigned int* __restrict__ cnt,
                               int* __restrict__ sorted) {
    __shared__ unsigned int lcnt[NE];
    __shared__ unsigned int lbase[NE];
    int t = threadIdx.x;
    if (t < NE) lcnt[t] = 0u;
    __syncthreads();
    int i = blockIdx.x * 256 + t;
    int e = wid[i];
    unsigned int lpos = atomicAdd(&lcnt[e], 1u);
    __syncthreads();
    if (t < NE) lbase[t] = atomicAdd(&cnt[t], lcnt[t]);
    __syncthreads();
    sorted[e * NB + (int)(lbase[e] + lpos)] = i;
}

// ---------------------------------------------------------------------------
// gemm R8: max-MLP staging + max occupancy + zero phase idling.
//   R0/R5 (16 waves/CU, VGPR-starved staging) = 54 us; R7 (8 waves/CU,
//   global_load_lds but 2-of-4-waves-per-phase serialization) = 78 us.
//   R8 combines: 1024 blocks x 512 thr (16 waves/CU, 2 blocks/CU), 32-row
//   fp32 tile in LDS via global_load_lds (8 x 1KB fire-and-forget per wave,
//   no VGPR), ONE barrier, then every wave runs its full 32 MFMAs.
// LDS [32 rows][512 floats] linear (64 KB). Stage instr (r, h): dest
//   &ldsf[r][h*256], lane l -> cb = h*2+(l>>5), chunk slot l&31 holding
//   global chunk (l&31)^(r&7)  (rule #21: swizzle on SOURCE, linear dest).
// Fragment read (row m0=lane&31, global chunk gj): LDS chunk gj^(m0&7)
//   -> residual 4-way bank conflict (structural for 512B-stride rows), ~1us.
// Wave w: kout=w>>1, nhalf=w&1; out = 32 rows x 64 cols; K=256 from x
//   col-blocks {kout (seg kout), (kout+3)&3 (seg +4, x0.5 pre-folded)}.
// B-frags for c=0 preloaded into VGPRs BEFORE the barrier (L2 latency hides
//   under the x drain). Fast single-expert path; masked path for <=3
//   boundary blocks (block-uniform branch; barrier inside both arms).
// ---------------------------------------------------------------------------
__global__ __launch_bounds__(512, 4) void gemm_kernel(
        const float* __restrict__ x, const unsigned short* __restrict__ wshuf,
        const unsigned int* __restrict__ cnt, const int* __restrict__ sorted,
        float* __restrict__ out) {
    const int rowbase = blockIdx.x * 32;
    __shared__ float ldsf[32][512];   // 64 KB
    __shared__ int rowid[32];

    const unsigned int p1 = cnt[0];
    const unsigned int p2 = p1 + cnt[1];
    const unsigned int p3 = p2 + cnt[2];

    const int t = threadIdx.x;
    const int w = t >> 6, lane = t & 63;
    const int l5 = lane >> 5, m0 = lane & 31;
    const int kout = w >> 1, nhalf = w & 1;

    // ---- row ids for this wave's 4 staged rows (rows 4w..4w+3) ----
    int rid[4];
#pragma unroll
    for (int i = 0; i < 4; i++) {
        unsigned int ls = (unsigned int)(rowbase + 4 * w + i);
        int e = (ls >= p1) + (ls >= p2) + (ls >= p3);
        unsigned int pe = (e == 0) ? 0u : (e == 1) ? p1 : (e == 2) ? p2 : p3;
        rid[i] = sorted[e * NB + (int)(ls - pe)];
    }
    if (t < 32) {
        unsigned int ls = (unsigned int)(rowbase + t);
        int e = (ls >= p1) + (ls >= p2) + (ls >= p3);
        unsigned int pe = (e == 0) ? 0u : (e == 1) ? p1 : (e == 2) ? p2 : p3;
        rowid[t] = sorted[e * NB + (int)(ls - pe)];
    }

    // ---- stage: 4 rows x 2 half-row instrs, all fire-and-forget ----
#pragma unroll
    for (int i = 0; i < 4; i++) {
        int r = 4 * w + i;
        int rs = r & 7;
        const float* xb = x + (size_t)rid[i] * IN_STRIDE + ((m0 ^ rs) << 2) + l5 * 128;
#pragma unroll
        for (int h = 0; h < 2; h++) {
            __builtin_amdgcn_global_load_lds(
                (const __attribute__((address_space(1))) unsigned int*)(xb + h * 256),
                (__attribute__((address_space(3))) unsigned int*)&ldsf[r][h * 256],
                16, 0, 0);
        }
    }

    // expert span / per-lane expert
    const unsigned int lh = (unsigned int)rowbase, lt = (unsigned int)(rowbase + 31);
    const int ehead = (lh >= p1) + (lh >= p2) + (lh >= p3);
    const int etail = (lt >= p1) + (lt >= p2) + (lt >= p3);
    const unsigned int l0 = (unsigned int)(rowbase + m0);
    const int e0 = (l0 >= p1) + (l0 >= p2) + (l0 >= p3);

    const int xbc1 = (kout + 3) & 3;
    const int xbs[2] = {kout, xbc1};
    const int sgs[2] = {kout, xbc1 + 4};
    const int rsw = m0 & 7;

    f32x16 acc0 = {}, acc1 = {};

    if (ehead == etail) {
        // ---- fast path: whole 32-row tile is one expert ----
        // preload c=0 B-frags kt=0..3 (both nt) before the barrier
        const unsigned short* wb0 =
            wshuf + (size_t)(((ehead * 8 + sgs[0]) * 4 + nhalf * 2) * 8) * 512 + (size_t)lane * 8;
        u32x4 bp[8];
#pragma unroll
        for (int kt = 0; kt < 4; kt++) {
            bp[kt * 2]     = *(const u32x4*)(wb0 + (size_t)kt * 512);
            bp[kt * 2 + 1] = *(const u32x4*)(wb0 + (size_t)(8 + kt) * 512);
        }
        __syncthreads();   // drains vmcnt(0): x-stage AND B-preload

#pragma unroll
        for (int c = 0; c < 2; c++) {
            const float* ar = &ldsf[m0][xbs[c] * 128];
            const unsigned short* wb =
                wshuf + (size_t)(((ehead * 8 + sgs[c]) * 4 + nhalf * 2) * 8) * 512 + (size_t)lane * 8;
#pragma unroll
            for (int kt = 0; kt < 8; kt++) {
                int gj0 = kt * 4 + l5 * 2;
                float4 va = *(const float4*)(ar + ((gj0 ^ rsw) << 2));
                float4 vb = *(const float4*)(ar + (((gj0 + 1) ^ rsw) << 2));
                bf16x8 a;
                a[0] = (__bf16)va.x; a[1] = (__bf16)va.y;
                a[2] = (__bf16)va.z; a[3] = (__bf16)va.w;
                a[4] = (__bf16)vb.x; a[5] = (__bf16)vb.y;
                a[6] = (__bf16)vb.z; a[7] = (__bf16)vb.w;
                bf16x8 b0, b1;
                if (c == 0 && kt < 4) {
                    b0 = __builtin_bit_cast(bf16x8, bp[kt * 2]);
                    b1 = __builtin_bit_cast(bf16x8, bp[kt * 2 + 1]);
                } else {
                    b0 = __builtin_bit_cast(bf16x8, *(const u32x4*)(wb + (size_t)kt * 512));
                    b1 = __builtin_bit_cast(bf16x8, *(const u32x4*)(wb + (size_t)(8 + kt) * 512));
                }
                acc0 = __builtin_amdgcn_mfma_f32_32x32x16_bf16(a, b0, acc0, 0, 0, 0);
                acc1 = __builtin_amdgcn_mfma_f32_32x32x16_bf16(a, b1, acc1, 0, 0, 0);
            }
        }
    } else {
        // ---- boundary block (<=3 of 1024): masked 4-expert path ----
        unsigned int msk[4];
#pragma unroll
        for (int e = 0; e < 4; e++) msk[e] = (e0 == e) ? 0xFFFFFFFFu : 0u;
        __syncthreads();
#pragma unroll
        for (int c = 0; c < 2; c++) {
            const float* ar = &ldsf[m0][xbs[c] * 128];
#pragma unroll
            for (int kt = 0; kt < 8; kt++) {
                int gj0 = kt * 4 + l5 * 2;
                float4 va = *(const float4*)(ar + ((gj0 ^ rsw) << 2));
                float4 vb = *(const float4*)(ar + (((gj0 + 1) ^ rsw) << 2));
                __attribute__((aligned(16))) unsigned short au[8];
                au[0] = f2bf(va.x); au[1] = f2bf(va.y);
                au[2] = f2bf(va.z); au[3] = f2bf(va.w);
                au[4] = f2bf(vb.x); au[5] = f2bf(vb.y);
                au[6] = f2bf(vb.z); au[7] = f2bf(vb.w);
                u32x4 araw = *(const u32x4*)au;
#pragma unroll
                for (int e = 0; e < 4; e++) {
                    u32x4 mm = {msk[e], msk[e], msk[e], msk[e]};
                    bf16x8 am = __builtin_bit_cast(bf16x8, araw & mm);
                    const unsigned short* wb =
                        wshuf + (size_t)(((e * 8 + sgs[c]) * 4 + nhalf * 2) * 8) * 512 + (size_t)lane * 8;
                    bf16x8 b0 = __builtin_bit_cast(bf16x8, *(const u32x4*)(wb + (size_t)kt * 512));
                    bf16x8 b1 = __builtin_bit_cast(bf16x8, *(const u32x4*)(wb + (size_t)(8 + kt) * 512));
                    acc0 = __builtin_amdgcn_mfma_f32_32x32x16_bf16(am, b0, acc0, 0, 0, 0);
                    acc1 = __builtin_amdgcn_mfma_f32_32x32x16_bf16(am, b1, acc1, 0, 0, 0);
                }
            }
        }
    }

    // ---- epilogue: C/D layout col=lane&31, row=(reg&3)+8*(reg>>2)+4*(lane>>5)
    // per store instr: 2 x 128B contiguous segments (rows via rowid).
    const int colb = kout * 128 + nhalf * 64 + m0;
    const int rh = l5 << 2;
#pragma unroll
    for (int q = 0; q < 4; q++) {
#pragma unroll
        for (int d = 0; d < 4; d++) {
            int reg = q * 4 + d;
            int rl = d + 8 * q + rh;
            float* o = out + (size_t)rowid[rl] * OUT_STRIDE + colb;
            o[0]  = acc0[reg];
            o[32] = acc1[reg];
        }
    }
}

extern "C" void kernel_launch(void* const* d_in, const int* in_sizes, int n_in,
                              void* d_out, int out_size, void* d_ws, size_t ws_size,
                              hipStream_t stream) {
    const float* x = (const float*)d_in[0];
    const float* w = (const float*)d_in[1];
    const int* wid = (const int*)d_in[2];
    float* out = (float*)d_out;

    unsigned short* wshuf = (unsigned short*)((char*)d_ws + WS_WSHUF);
    unsigned int* cnt = (unsigned int*)((char*)d_ws + WS_CNT);
    int* sorted = (int*)((char*)d_ws + WS_SORT);

    prep_kernel<<<256, 256, 0, stream>>>(w, wshuf, cnt);
    scatter_kernel<<<128, 256, 0, stream>>>(wid, cnt, sorted);
    gemm_kernel<<<1024, 512, 0, stream>>>(x, wshuf, cnt, sorted, out);
}